// Round 1
// baseline (269.870 us; speedup 1.0000x reference)
//
#include <hip/hip_runtime.h>

// RBF layer, algebraically collapsed:
//   out[n,o] = Bo[o] - x2[n]*S1[o] + 2 * sum_d x[n,d] * M[d,o]
// where (all tiny, precomputed per launch from the constant inputs):
//   s[d]  = relu(sigma[d]);  w[k] = relu(width[k]);  Wr = relu(output_weights)
//   M[d,o]  = s[d] * sum_k center[k,d]*w[k]*Wr[1+k,o]          [256 x 128]
//   S1[o]   = sum_k w[k]*Wr[1+k,o]
//   c2[k]   = sum_d center[k,d]^2 * s[d]
//   Bo[o]   = Wr[0,o] + sum_k Wr[1+k,o] - sum_k c2[k]*w[k]*Wr[1+k,o]
//   x2[n]   = sum_d s[d]*x[n,d]^2   (fp32, computed in the main kernel)
// Main GEMM term uses bf16 MFMA 16x16x32; error contribution ~0.1 abs vs
// threshold ~1075 (dominant x2*S1 term stays fp32).

typedef short  short8 __attribute__((ext_vector_type(8)));
typedef __bf16 bf16x8 __attribute__((ext_vector_type(8)));
typedef float  f32x4  __attribute__((ext_vector_type(4)));

#define N_ 131072
#define D_ 256
#define K_ 256
#define O_ 128

// ws layout: Mfrag bf16 (pre-swizzled B-fragments) at 0, 64 KiB;
//            Bo fp32 at 65536 (512 B); S1 fp32 at 66048 (512 B). Needs 66.5 KiB.

__device__ __forceinline__ unsigned short f2bf_bits(float f) {
  unsigned u = __builtin_bit_cast(unsigned, f);
  u += 0x7fffu + ((u >> 16) & 1u);   // round-to-nearest-even
  return (unsigned short)(u >> 16);
}

__device__ __forceinline__ float relu(float v) { return v > 0.f ? v : 0.f; }

// ---- Precompute kernel: 65 blocks x 256 threads ---------------------------
// blocks 0..63: Mfrag[ks][ot][lane][j] = bf16( s[d] * sum_k c[k,d]*w[k]*Wr[1+k,o] )
//   with d = ks*32 + (lane>>4)*8 + j, o = ot*16 + (lane&15)  (exact MFMA B layout)
// block 64: c2[k] -> LDS, then Bo[o], S1[o].
__global__ __launch_bounds__(256) void rbf_pre(
    const float* __restrict__ center, const float* __restrict__ sigma,
    const float* __restrict__ width,  const float* __restrict__ W,
    short* __restrict__ Mfrag, float* __restrict__ Bo, float* __restrict__ S1)
{
  const int tid = threadIdx.x;
  if (blockIdx.x < 64) {
#pragma unroll
    for (int rep = 0; rep < 2; ++rep) {
      const int e    = blockIdx.x * 512 + rep * 256 + tid;  // 0..32767
      const int j    = e & 7;
      const int lane = (e >> 3) & 63;
      const int ot   = (e >> 9) & 7;
      const int ks   = (e >> 12) & 7;
      const int d = ks * 32 + (lane >> 4) * 8 + j;
      const int o = ot * 16 + (lane & 15);
      float acc = 0.f;
      for (int k = 0; k < K_; ++k) {
        const float w  = relu(width[k]);
        const float wr = relu(W[(1 + k) * O_ + o]);
        acc = fmaf(center[k * D_ + d] * w, wr, acc);
      }
      Mfrag[e] = (short)f2bf_bits(acc * relu(sigma[d]));
    }
  } else {
    __shared__ float c2s[K_];
    {
      const int k = tid;
      float acc = 0.f;
      for (int d = 0; d < D_; ++d) {
        const float c = center[k * D_ + d];
        acc = fmaf(c * c, relu(sigma[d]), acc);
      }
      c2s[k] = acc;
    }
    __syncthreads();
    if (tid < O_) {
      const int o = tid;
      float s1 = 0.f, sum = 0.f, c2w = 0.f;
      for (int k = 0; k < K_; ++k) {
        const float w  = relu(width[k]);
        const float wr = relu(W[(1 + k) * O_ + o]);
        s1  = fmaf(w, wr, s1);
        sum += wr;
        c2w = fmaf(c2s[k] * w, wr, c2w);
      }
      Bo[o] = relu(W[o]) + sum - c2w;
      S1[o] = s1;
    }
  }
}

// ---- Main kernel: 2048 blocks x 256 threads (4 waves), 16 rows per wave ---
__global__ __launch_bounds__(256) void rbf_main(
    const float* __restrict__ x, const float* __restrict__ sigma,
    const short* __restrict__ Mfrag, const float* __restrict__ Bo,
    const float* __restrict__ S1, float* __restrict__ out)
{
  const int lane = threadIdx.x & 63;
  const int wv   = threadIdx.x >> 6;
  const int m    = lane & 15;      // A row within tile / C col within tile
  const int q    = lane >> 4;      // quad
  const long rowBase = ((long)blockIdx.x * 4 + wv) * 16;

  const float* xr = x + (rowBase + m) * D_ + q * 8;
  const float* sp = sigma + q * 8;

  // Load 16x256 A-tile as bf16 fragments; accumulate fp32 x2 along the way.
  bf16x8 a[8];
  float x2p = 0.f;
#pragma unroll
  for (int ks = 0; ks < 8; ++ks) {
    float xv[8], sv[8];
    *(f32x4*)(xv)     = *(const f32x4*)(xr + ks * 32);
    *(f32x4*)(xv + 4) = *(const f32x4*)(xr + ks * 32 + 4);
    *(f32x4*)(sv)     = *(const f32x4*)(sp + ks * 32);
    *(f32x4*)(sv + 4) = *(const f32x4*)(sp + ks * 32 + 4);
    short8 ab;
#pragma unroll
    for (int j = 0; j < 8; ++j) {
      const float s = relu(sv[j]);
      const float v = xv[j];
      x2p = fmaf(s * v, v, x2p);
      ab[j] = (short)f2bf_bits(v);
    }
    a[ks] = __builtin_bit_cast(bf16x8, ab);
  }
  // Reduce x2 across the 4 lanes holding the same row (lanes m, m+16, m+32, m+48)
  x2p += __shfl_xor(x2p, 16);
  x2p += __shfl_xor(x2p, 32);
  // Now every lane with (lane&15)==r holds full x2 of row rowBase+r.

  const short8* Mf = (const short8*)Mfrag;
#pragma unroll
  for (int ot = 0; ot < 8; ++ot) {
    f32x4 acc = {0.f, 0.f, 0.f, 0.f};
#pragma unroll
    for (int ks = 0; ks < 8; ++ks) {
      const short8 bs = Mf[(ks * 8 + ot) * 64 + lane];
      acc = __builtin_amdgcn_mfma_f32_16x16x32_bf16(
          a[ks], __builtin_bit_cast(bf16x8, bs), acc, 0, 0, 0);
    }
    const int   o  = ot * 16 + m;          // C/D: col = lane&15
    const float bo = Bo[o];
    const float s1 = S1[o];
    float* op = out + rowBase * O_ + o;
#pragma unroll
    for (int r = 0; r < 4; ++r) {
      const int rr = q * 4 + r;            // C/D: row = (lane>>4)*4 + reg
      const float x2r = __shfl(x2p, rr);   // broadcast from lane rr (<16)
      op[(long)rr * O_] = fmaf(2.f, acc[r], fmaf(-x2r, s1, bo));
    }
  }
}

extern "C" void kernel_launch(void* const* d_in, const int* in_sizes, int n_in,
                              void* d_out, int out_size, void* d_ws, size_t ws_size,
                              hipStream_t stream) {
  (void)in_sizes; (void)n_in; (void)out_size; (void)ws_size;
  const float* x      = (const float*)d_in[0];
  const float* center = (const float*)d_in[1];
  const float* sigma  = (const float*)d_in[2];
  const float* width  = (const float*)d_in[3];
  const float* W      = (const float*)d_in[4];
  float* out = (float*)d_out;

  short* Mfrag = (short*)d_ws;                       // 64 KiB
  float* Bo    = (float*)((char*)d_ws + 65536);      // 512 B
  float* S1    = (float*)((char*)d_ws + 66048);      // 512 B

  hipLaunchKernelGGL(rbf_pre, dim3(65), dim3(256), 0, stream,
                     center, sigma, width, W, Mfrag, Bo, S1);
  hipLaunchKernelGGL(rbf_main, dim3(2048), dim3(256), 0, stream,
                     x, sigma, Mfrag, Bo, S1, out);
}

// Round 2
// 260.440 us; speedup vs baseline: 1.0362x; 1.0362x over previous
//
#include <hip/hip_runtime.h>

// RBF layer, algebraically collapsed:
//   out[n,o] = Bo[o] - x2[n]*S1[o] + 2 * sum_d x[n,d] * M[d,o]
// where (all tiny, precomputed per launch from the constant inputs):
//   s[d]  = relu(sigma[d]);  w[k] = relu(width[k]);  Wr = relu(output_weights)
//   M[d,o]  = s[d] * sum_k center[k,d]*w[k]*Wr[1+k,o]          [256 x 128]
//   S1[o]   = sum_k w[k]*Wr[1+k,o]
//   c2[k]   = sum_d center[k,d]^2 * s[d]
//   Bo[o]   = Wr[0,o] + sum_k Wr[1+k,o] - sum_k c2[k]*w[k]*Wr[1+k,o]
//   x2[n]   = sum_d s[d]*x[n,d]^2   (fp32, computed in the main kernel)
// Main GEMM term uses bf16 MFMA 16x16x32 (abs-err contribution ~0.1 vs
// threshold ~1075; dominant x2*S1 term stays fp32).

typedef short  short8 __attribute__((ext_vector_type(8)));
typedef __bf16 bf16x8 __attribute__((ext_vector_type(8)));
typedef float  f32x4  __attribute__((ext_vector_type(4)));

#define N_ 131072
#define D_ 256
#define K_ 256
#define O_ 128

__device__ __forceinline__ unsigned short f2bf_bits(float f) {
  unsigned u = __builtin_bit_cast(unsigned, f);
  u += 0x7fffu + ((u >> 16) & 1u);   // round-to-nearest-even
  return (unsigned short)(u >> 16);
}

__device__ __forceinline__ float relu(float v) { return v > 0.f ? v : 0.f; }

// ---- Precompute kernel: 65 blocks x 256 threads ---------------------------
// Blocks 0..63: one (ks,ot) B-fragment tile of M each (32 d x 16 o), with
// ww[k][oc]=relu(w)*relu(Wr) and cen[k][dc] staged in LDS so the 256-deep
// k-loop is pure LDS (conflict-free: all reads are broadcasts across lanes).
// Block 64: c2 -> LDS, then Bo[o], S1[o].
__global__ __launch_bounds__(256) void rbf_pre(
    const float* __restrict__ center, const float* __restrict__ sigma,
    const float* __restrict__ width,  const float* __restrict__ W,
    short* __restrict__ Mfrag, float* __restrict__ Bo, float* __restrict__ S1)
{
  const int tid = threadIdx.x;
  if (blockIdx.x < 64) {
    const int ot = blockIdx.x & 7;
    const int ks = blockIdx.x >> 3;
    __shared__ float ww[K_][16];   // 16 KB
    __shared__ float cen[K_][32];  // 32 KB
#pragma unroll
    for (int i = 0; i < 16; ++i) {
      const int k  = i * 16 + (tid >> 4);
      const int oc = tid & 15;
      ww[k][oc] = relu(width[k]) * relu(W[(1 + k) * O_ + ot * 16 + oc]);
    }
#pragma unroll
    for (int i = 0; i < 32; ++i) {
      const int k  = i * 8 + (tid >> 5);
      const int dc = tid & 31;
      cen[k][dc] = center[k * D_ + ks * 32 + dc];
    }
    __syncthreads();
    const int j   = tid & 7;
    const int lf  = tid >> 3;              // 0..31 == MFMA lane field
    const int oc  = lf & 15;
    const int dc1 = (lf >> 4) * 8 + j;     // 0..15
    float a1 = 0.f, a2 = 0.f;
#pragma unroll 8
    for (int k = 0; k < K_; ++k) {
      const float w = ww[k][oc];
      a1 = fmaf(cen[k][dc1],      w, a1);
      a2 = fmaf(cen[k][dc1 + 16], w, a2);
    }
    const int e1 = blockIdx.x * 512 + tid;
    const int d1 = ks * 32 + dc1;
    Mfrag[e1]       = (short)f2bf_bits(a1 * relu(sigma[d1]));
    Mfrag[e1 + 256] = (short)f2bf_bits(a2 * relu(sigma[d1 + 16]));
  } else {
    __shared__ float c2s[K_];
    {
      const int k = tid;
      float acc = 0.f;
      for (int d = 0; d < D_; ++d) {
        const float c = center[k * D_ + d];
        acc = fmaf(c * c, relu(sigma[d]), acc);
      }
      c2s[k] = acc;
    }
    __syncthreads();
    if (tid < O_) {
      const int o = tid;
      float s1 = 0.f, sum = 0.f, c2w = 0.f;
      for (int k = 0; k < K_; ++k) {
        const float w  = relu(width[k]);
        const float wr = relu(W[(1 + k) * O_ + o]);
        s1  = fmaf(w, wr, s1);
        sum += wr;
        c2w = fmaf(c2s[k] * w, wr, c2w);
      }
      Bo[o] = relu(W[o]) + sum - c2w;
      S1[o] = s1;
    }
  }
}

// ---- Main kernel: 1024 blocks x 256 threads (4 waves), 32 rows per wave ---
// All 32 x-load dwordx4 issued up-front (32 KB MLP per wave); B fragments
// loaded once per ot and reused across the two 16-row tiles.
__global__ __launch_bounds__(256, 2) void rbf_main(
    const float* __restrict__ x, const float* __restrict__ sigma,
    const short* __restrict__ Mfrag, const float* __restrict__ Bo,
    const float* __restrict__ S1, float* __restrict__ out)
{
  const int lane = threadIdx.x & 63;
  const int wv   = threadIdx.x >> 6;
  const int m    = lane & 15;      // A row within tile / C col within tile
  const int q    = lane >> 4;      // quad
  const long rowBase = ((long)blockIdx.x * 4 + wv) * 32;

  const float* xr0 = x + (rowBase + m) * D_ + q * 8;
  const float* xr1 = xr0 + 16 * D_;

  // Issue ALL global x loads first: 32 dwordx4 in flight.
  f32x4 raw0[16], raw1[16];
#pragma unroll
  for (int ks = 0; ks < 8; ++ks) {
    raw0[ks * 2]     = *(const f32x4*)(xr0 + ks * 32);
    raw0[ks * 2 + 1] = *(const f32x4*)(xr0 + ks * 32 + 4);
  }
#pragma unroll
  for (int ks = 0; ks < 8; ++ks) {
    raw1[ks * 2]     = *(const f32x4*)(xr1 + ks * 32);
    raw1[ks * 2 + 1] = *(const f32x4*)(xr1 + ks * 32 + 4);
  }

  // Convert to bf16 A-fragments; accumulate fp32 x2 along the way.
  const float* sp = sigma + q * 8;
  bf16x8 a0[8], a1[8];
  float x20 = 0.f, x21 = 0.f;
#pragma unroll
  for (int ks = 0; ks < 8; ++ks) {
    float sv[8], v0[8], v1[8];
    *(f32x4*)(sv)     = *(const f32x4*)(sp + ks * 32);
    *(f32x4*)(sv + 4) = *(const f32x4*)(sp + ks * 32 + 4);
    *(f32x4*)(v0)     = raw0[ks * 2];
    *(f32x4*)(v0 + 4) = raw0[ks * 2 + 1];
    *(f32x4*)(v1)     = raw1[ks * 2];
    *(f32x4*)(v1 + 4) = raw1[ks * 2 + 1];
    short8 b0, b1;
#pragma unroll
    for (int jj = 0; jj < 8; ++jj) {
      const float s = relu(sv[jj]);
      x20 = fmaf(s * v0[jj], v0[jj], x20);
      x21 = fmaf(s * v1[jj], v1[jj], x21);
      b0[jj] = (short)f2bf_bits(v0[jj]);
      b1[jj] = (short)f2bf_bits(v1[jj]);
    }
    a0[ks] = __builtin_bit_cast(bf16x8, b0);
    a1[ks] = __builtin_bit_cast(bf16x8, b1);
  }
  // Reduce x2 across the 4 lanes holding the same row.
  x20 += __shfl_xor(x20, 16);  x20 += __shfl_xor(x20, 32);
  x21 += __shfl_xor(x21, 16);  x21 += __shfl_xor(x21, 32);

  // Per-lane epilogue constants for all 8 o-tiles.
  float bo[8], s1v[8];
#pragma unroll
  for (int ot = 0; ot < 8; ++ot) {
    bo[ot]  = Bo[ot * 16 + m];
    s1v[ot] = S1[ot * 16 + m];
  }

  const short8* Mf = (const short8*)Mfrag;
#pragma unroll
  for (int ot = 0; ot < 8; ++ot) {
    f32x4 acc0 = {0.f, 0.f, 0.f, 0.f};
    f32x4 acc1 = {0.f, 0.f, 0.f, 0.f};
#pragma unroll
    for (int ks = 0; ks < 8; ++ks) {
      const short8 bs = Mf[(ks * 8 + ot) * 64 + lane];
      const bf16x8 bb = __builtin_bit_cast(bf16x8, bs);
      acc0 = __builtin_amdgcn_mfma_f32_16x16x32_bf16(a0[ks], bb, acc0, 0, 0, 0);
      acc1 = __builtin_amdgcn_mfma_f32_16x16x32_bf16(a1[ks], bb, acc1, 0, 0, 0);
    }
    const int o = ot * 16 + m;             // C/D: col = lane&15
    float* op0 = out + rowBase * O_ + o;
    float* op1 = op0 + 16 * O_;
#pragma unroll
    for (int r = 0; r < 4; ++r) {
      const int rr = q * 4 + r;            // C/D: row = (lane>>4)*4 + reg
      const float x2r0 = __shfl(x20, rr);
      const float x2r1 = __shfl(x21, rr);
      __builtin_nontemporal_store(
          fmaf(2.f, acc0[r], fmaf(-x2r0, s1v[ot], bo[ot])), op0 + (long)rr * O_);
      __builtin_nontemporal_store(
          fmaf(2.f, acc1[r], fmaf(-x2r1, s1v[ot], bo[ot])), op1 + (long)rr * O_);
    }
  }
}

extern "C" void kernel_launch(void* const* d_in, const int* in_sizes, int n_in,
                              void* d_out, int out_size, void* d_ws, size_t ws_size,
                              hipStream_t stream) {
  (void)in_sizes; (void)n_in; (void)out_size; (void)ws_size;
  const float* x      = (const float*)d_in[0];
  const float* center = (const float*)d_in[1];
  const float* sigma  = (const float*)d_in[2];
  const float* width  = (const float*)d_in[3];
  const float* W      = (const float*)d_in[4];
  float* out = (float*)d_out;

  short* Mfrag = (short*)d_ws;                       // 64 KiB
  float* Bo    = (float*)((char*)d_ws + 65536);      // 512 B
  float* S1    = (float*)((char*)d_ws + 66048);      // 512 B

  hipLaunchKernelGGL(rbf_pre, dim3(65), dim3(256), 0, stream,
                     center, sigma, width, W, Mfrag, Bo, S1);
  hipLaunchKernelGGL(rbf_main, dim3(1024), dim3(256), 0, stream,
                     x, sigma, Mfrag, Bo, S1, out);
}